// Round 15
// baseline (253.474 us; speedup 1.0000x reference)
//
#include <hip/hip_runtime.h>
#include <hip/hip_fp16.h>

typedef _Float16 half8 __attribute__((ext_vector_type(8)));
typedef float f32x16 __attribute__((ext_vector_type(16)));

constexpr int M = 2048;    // B*S
constexpr int N = 10240;   // DOUT
constexpr int K = 4096;    // DIN

// ---------------------------------------------------------------------------
// Fused pre-pass: A fp32->fp16 (exact) + W fp32 -> fp16*fp16(scale)
// (bit-identical to reference). Branch is block-uniform except one block.
constexpr long A_VEC = (long)M * K / 8;   // 1,048,576
constexpr long W_VEC = (long)N * K / 8;   // 5,242,880

__global__ __launch_bounds__(256)
void prep_kernel(const float* __restrict__ A, const float* __restrict__ W,
                 const float* __restrict__ Wsc,
                 _Float16* __restrict__ Ah, _Float16* __restrict__ Wh) {
    const long total = A_VEC + W_VEC;
    for (long i = (long)blockIdx.x * blockDim.x + threadIdx.x; i < total;
         i += (long)gridDim.x * blockDim.x) {
        if (i < A_VEC) {
            const long base = i * 8;
            const float4 a0 = ((const float4*)(A + base))[0];
            const float4 a1 = ((const float4*)(A + base))[1];
            half8 h;
            h[0] = (_Float16)a0.x; h[1] = (_Float16)a0.y;
            h[2] = (_Float16)a0.z; h[3] = (_Float16)a0.w;
            h[4] = (_Float16)a1.x; h[5] = (_Float16)a1.y;
            h[6] = (_Float16)a1.z; h[7] = (_Float16)a1.w;
            *(half8*)(Ah + base) = h;
        } else {
            const long base = (i - A_VEC) * 8;
            const int row = (int)(base >> 12);           // / K
            const _Float16 s = (_Float16)Wsc[row];
            const float4 w0 = ((const float4*)(W + base))[0];
            const float4 w1 = ((const float4*)(W + base))[1];
            half8 h;
            h[0] = (_Float16)w0.x * s; h[1] = (_Float16)w0.y * s;
            h[2] = (_Float16)w0.z * s; h[3] = (_Float16)w0.w * s;
            h[4] = (_Float16)w1.x * s; h[5] = (_Float16)w1.y * s;
            h[6] = (_Float16)w1.z * s; h[7] = (_Float16)w1.w * s;
            *(half8*)(Wh + base) = h;
        }
    }
}

// ---------------------------------------------------------------------------
// GEMM: r11 skeleton (256x320, zero tail, kh/ks-split 3-phase, 2 barriers +
// counted vmcnt(9)/tile, T2 swizzle) with ROUND-15 change: 32x32x16 MFMA
// (µbench ceiling 2382-2495 TF vs 2075 for 16x16; half the instruction
// count). Waves: 8 = 4M x 2N of 64x160; acc[2][5] f32x16 = 160 AGPR.
// A/B frag: row/col = lane&31, k-chunk = (lane>>5)*8 (16B ds_read_b128).
// C/D: col = lane&31, row = (reg&3) + 8*(reg>>2) + 4*(lane>>5)  [m74/m101].
constexpr int BM = 256, BN = 320, BK = 64;
constexpr int AELE = BM * BK;   // 16384 fp16 = 32 KB
constexpr int BELE = BN * BK;   // 20480 fp16 = 40 KB
constexpr int NT = K / BK;      // 64 K-tiles

#define BAR()   asm volatile("s_barrier" ::: "memory")
#define LGKM0() asm volatile("s_waitcnt lgkmcnt(0)" ::: "memory")

__device__ __forceinline__ half8 lds_rd(const _Float16* base, int row, int eo) {
    // T2: physical 16B slot = slot ^ (row&7)
    const int ps = (eo >> 3) ^ (row & 7);
    return *(const half8*)(base + row * BK + ps * 8);
}

__global__ __launch_bounds__(512, 2)
void qgemm32x32_kernel(const _Float16* __restrict__ Ag,  // [M,K] fp16 (ws)
                       const _Float16* __restrict__ Wg,  // [N,K] fp16 deq
                       const float*    __restrict__ bias,
                       float*          __restrict__ C)
{
    __shared__ _Float16 AsF[2 * AELE];   // 64 KB
    __shared__ _Float16 BsF[2 * BELE];   // 80 KB  (144 KB total)

    // XCD-bijective swizzle: 256 = 8 chunks x 32; brow-fast -> 8-block runs
    // share one 2.6MB B panel (L2-resident per XCD).
    const int orig = blockIdx.x;
    const int wgid = (orig & 7) * 32 + (orig >> 3);
    const int m0 = (wgid & 7) * BM;
    const int n0 = (wgid >> 3) * BN;

    const int tid  = threadIdx.x;
    const int lane = tid & 63;
    const int w    = tid >> 6;
    const int wm   = w >> 1;            // 0..3 -> rows wm*64
    const int wn   = w & 1;             // 0..1 -> cols wn*160
    const int l31  = lane & 31;
    const int kq   = (lane >> 5) * 8;   // k-chunk element offset

    const int trow  = tid >> 3;                        // staging row 0..63
    const int swcol = (((tid & 7) ^ (trow & 7))) * 8;  // pre-swizzled src col

    // stage unit = 64 rows x 64 cols fp16 = 8 KB = 512 thr x 16 B
    auto stage_a = [&](int b, int u, int kcol) {
        const _Float16* src = Ag + (size_t)(m0 + u * 64 + trow) * K + (kcol + swcol);
        __builtin_amdgcn_global_load_lds(
            (const __attribute__((address_space(1))) void*)src,
            (__attribute__((address_space(3))) void*)(AsF + b * AELE + u * 4096 + tid * 8),
            16, 0, 0);
    };
    auto stage_b = [&](int b, int u, int kcol) {
        const _Float16* src = Wg + (size_t)(n0 + u * 64 + trow) * K + (kcol + swcol);
        __builtin_amdgcn_global_load_lds(
            (const __attribute__((address_space(1))) void*)src,
            (__attribute__((address_space(3))) void*)(BsF + b * BELE + u * 4096 + tid * 8),
            16, 0, 0);
    };

    f32x16 acc[2][5];
#pragma unroll
    for (int i = 0; i < 2; ++i)
#pragma unroll
        for (int j = 0; j < 5; ++j)
#pragma unroll
            for (int r = 0; r < 16; ++r)
                acc[i][j][r] = 0.f;

    // prologue: tile0 -> buf0 (9 loads), tile1 -> buf1 (9 loads)
#pragma unroll
    for (int u = 0; u < 4; ++u) stage_a(0, u, 0);
#pragma unroll
    for (int u = 0; u < 5; ++u) stage_b(0, u, 0);
#pragma unroll
    for (int u = 0; u < 4; ++u) stage_a(1, u, BK);
#pragma unroll
    for (int u = 0; u < 5; ++u) stage_b(1, u, BK);
    asm volatile("s_waitcnt vmcnt(9)" ::: "memory");   // tile0 landed
    BAR();

    const int rowA = wm * 64 + l31;      // A fragment row base
    const int rowB = wn * 160 + l31;     // B fragment row base

#pragma unroll 1
    for (int t = 0; t < NT; ++t) {
        const int cur = t & 1;
        const _Float16* Ab = AsF + cur * AELE;
        const _Float16* Bb = BsF + cur * BELE;
        const bool pf2 = (t + 2 < NT);
        const int k2 = (t + 2) * BK;

        // ---- P0: reads ks0/ks1 (b 10, a 4), 20 MFMA (all rb x cb x ks01)
        {
            half8 b0[5][2], a0[2][2];
#pragma unroll
            for (int cb = 0; cb < 5; ++cb)
#pragma unroll
                for (int ks = 0; ks < 2; ++ks)
                    b0[cb][ks] = lds_rd(Bb, rowB + cb * 32, ks * 16 + kq);
#pragma unroll
            for (int rb = 0; rb < 2; ++rb)
#pragma unroll
                for (int ks = 0; ks < 2; ++ks)
                    a0[rb][ks] = lds_rd(Ab, rowA + rb * 32, ks * 16 + kq);
            __builtin_amdgcn_s_setprio(1);
#pragma unroll
            for (int cb = 0; cb < 5; ++cb)
#pragma unroll
                for (int rb = 0; rb < 2; ++rb)
#pragma unroll
                    for (int ks = 0; ks < 2; ++ks)
                        acc[rb][cb] = __builtin_amdgcn_mfma_f32_32x32x16_f16(
                            a0[rb][ks], b0[cb][ks], acc[rb][cb], 0, 0, 0);
            __builtin_amdgcn_s_setprio(0);
        }

        // ---- P1: reads ks2/ks3 (14), 10 MFMA (rb 0); LGKM0+BAR frees bufs
        half8 b1[5][2], a1[2][2];
#pragma unroll
        for (int cb = 0; cb < 5; ++cb)
#pragma unroll
            for (int ks = 0; ks < 2; ++ks)
                b1[cb][ks] = lds_rd(Bb, rowB + cb * 32, 32 + ks * 16 + kq);
#pragma unroll
        for (int rb = 0; rb < 2; ++rb)
#pragma unroll
            for (int ks = 0; ks < 2; ++ks)
                a1[rb][ks] = lds_rd(Ab, rowA + rb * 32, 32 + ks * 16 + kq);
        __builtin_amdgcn_s_setprio(1);
#pragma unroll
        for (int cb = 0; cb < 5; ++cb)
#pragma unroll
            for (int ks = 0; ks < 2; ++ks)
                acc[0][cb] = __builtin_amdgcn_mfma_f32_32x32x16_f16(
                    a1[0][ks], b1[cb][ks], acc[0][cb], 0, 0, 0);
        __builtin_amdgcn_s_setprio(0);
        LGKM0();   // all own reads of cur complete (cross-wave stage safety)
        BAR();     // every wave done reading A(cur)+B(cur)

        // ---- P2: stage t+2 into cur; 10 MFMA (rb 1, reg-only); vmcnt
        if (pf2) {
#pragma unroll
            for (int u = 0; u < 4; ++u) stage_a(cur, u, k2);
#pragma unroll
            for (int u = 0; u < 5; ++u) stage_b(cur, u, k2);
        }
        __builtin_amdgcn_s_setprio(1);
#pragma unroll
        for (int cb = 0; cb < 5; ++cb)
#pragma unroll
            for (int ks = 0; ks < 2; ++ks)
                acc[1][cb] = __builtin_amdgcn_mfma_f32_32x32x16_f16(
                    a1[1][ks], b1[cb][ks], acc[1][cb], 0, 0, 0);
        __builtin_amdgcn_s_setprio(0);
        if (pf2) asm volatile("s_waitcnt vmcnt(9)" ::: "memory");  // t+1 landed
        else     asm volatile("s_waitcnt vmcnt(0)" ::: "memory");  // tail drain
        BAR();   // publish t+1
    }

    // epilogue: 32x32 C/D layout col = lane&31, row = (reg&3)+8*(reg>>2)+4*(lane>>5)
    float bb[5];
#pragma unroll
    for (int j = 0; j < 5; ++j)
        bb[j] = bias[n0 + wn * 160 + j * 32 + l31];
    const int rbase = m0 + wm * 64 + 4 * (lane >> 5);
#pragma unroll
    for (int i = 0; i < 2; ++i) {
#pragma unroll
        for (int j = 0; j < 5; ++j) {
            const int col = n0 + wn * 160 + j * 32 + l31;
#pragma unroll
            for (int r = 0; r < 16; ++r) {
                const int row = rbase + i * 32 + (r & 3) + 8 * (r >> 2);
                C[(size_t)row * N + col] =
                    (float)(_Float16)(acc[i][j][r] + bb[j]);
            }
        }
    }
}

// ---------------------------------------------------------------------------
// Fallback (round-2 fused kernel, passing @434us) if ws too small.
__global__ __launch_bounds__(256, 2)
void qlinear_fused_kernel(const float* __restrict__ A, const float* __restrict__ W,
                          const float* __restrict__ Wsc, const float* __restrict__ bias,
                          float* __restrict__ C)
{
    typedef float f32x4 __attribute__((ext_vector_type(4)));
    __shared__ _Float16 As[128][64];
    __shared__ _Float16 Bs[128][64];

    const int nwg  = (M / 128) * (N / 128);
    const int orig = blockIdx.x;
    const int wgid = (orig & 7) * (nwg >> 3) + (orig >> 3);
    const int brow = wgid & (M / 128 - 1);
    const int bcol = wgid / (M / 128);
    const int m0 = brow * 128;
    const int n0 = bcol * 128;

    const int t    = threadIdx.x;
    const int lane = t & 63;
    const int wave = t >> 6;
    const int wr = (wave >> 1) * 64;
    const int wc = (wave & 1) * 64;
    const int fr = lane & 15;
    const int fk = (lane >> 4) * 8;
    const int srow = t >> 3;
    const int scol = (t & 7) * 8;

    _Float16 hs[4];
#pragma unroll
    for (int p = 0; p < 4; ++p)
        hs[p] = (_Float16)Wsc[n0 + srow + p * 32];

    f32x4 acc[4][4];
#pragma unroll
    for (int i = 0; i < 4; ++i)
#pragma unroll
        for (int j = 0; j < 4; ++j)
            acc[i][j] = (f32x4){0.f, 0.f, 0.f, 0.f};

    for (int k0 = 0; k0 < K; k0 += 64) {
        __syncthreads();
#pragma unroll
        for (int c = 0; c < 4; ++c) {
            const int rl = c * 32 + srow;
            const float* asrc = A + (size_t)(m0 + rl) * K + (k0 + scol);
            const float4 a0 = ((const float4*)asrc)[0];
            const float4 a1 = ((const float4*)asrc)[1];
            half8 av;
            av[0] = (_Float16)a0.x; av[1] = (_Float16)a0.y;
            av[2] = (_Float16)a0.z; av[3] = (_Float16)a0.w;
            av[4] = (_Float16)a1.x; av[5] = (_Float16)a1.y;
            av[6] = (_Float16)a1.z; av[7] = (_Float16)a1.w;
            *(half8*)&As[rl][scol] = av;
        }
#pragma unroll
        for (int p = 0; p < 4; ++p) {
            const int nl = srow + p * 32;
            const float* wsrc = W + (size_t)(n0 + nl) * K + (k0 + scol);
            const float4 w0 = ((const float4*)wsrc)[0];
            const float4 w1 = ((const float4*)wsrc)[1];
            half8 hv;
            hv[0] = (_Float16)w0.x * hs[p]; hv[1] = (_Float16)w0.y * hs[p];
            hv[2] = (_Float16)w0.z * hs[p]; hv[3] = (_Float16)w0.w * hs[p];
            hv[4] = (_Float16)w1.x * hs[p]; hv[5] = (_Float16)w1.y * hs[p];
            hv[6] = (_Float16)w1.z * hs[p]; hv[7] = (_Float16)w1.w * hs[p];
            *(half8*)&Bs[nl][scol] = hv;
        }
        __syncthreads();
#pragma unroll
        for (int kk = 0; kk < 64; kk += 32) {
            half8 av[4], bv[4];
#pragma unroll
            for (int i = 0; i < 4; ++i)
                av[i] = *(const half8*)&As[wr + i * 16 + fr][kk + fk];
#pragma unroll
            for (int j = 0; j < 4; ++j)
                bv[j] = *(const half8*)&Bs[wc + j * 16 + fr][kk + fk];
#pragma unroll
            for (int i = 0; i < 4; ++i)
#pragma unroll
                for (int j = 0; j < 4; ++j)
                    acc[i][j] = __builtin_amdgcn_mfma_f32_16x16x32_f16(
                        av[i], bv[j], acc[i][j], 0, 0, 0);
        }
    }
#pragma unroll
    for (int i = 0; i < 4; ++i) {
        const int row = m0 + wr + i * 16 + (lane >> 4) * 4;
#pragma unroll
        for (int j = 0; j < 4; ++j) {
            const int col = n0 + wc + j * 16 + fr;
            const float bbf = bias[col];
#pragma unroll
            for (int r = 0; r < 4; ++r)
                C[(size_t)(row + r) * N + col] =
                    (float)(_Float16)(acc[i][j][r] + bbf);
        }
    }
}

extern "C" void kernel_launch(void* const* d_in, const int* in_sizes, int n_in,
                              void* d_out, int out_size, void* d_ws, size_t ws_size,
                              hipStream_t stream) {
    const float* A    = (const float*)d_in[0];
    const float* W    = (const float*)d_in[1];
    const float* Wsc  = (const float*)d_in[2];
    const float* bias = (const float*)d_in[3];
    float* C = (float*)d_out;

    const size_t a_bytes = (size_t)M * K * sizeof(_Float16);   // 16.78 MB
    const size_t w_bytes = (size_t)N * K * sizeof(_Float16);   // 83.89 MB

    if (ws_size >= a_bytes + w_bytes) {
        _Float16* Ah = (_Float16*)d_ws;
        _Float16* Wh = (_Float16*)((char*)d_ws + a_bytes);
        prep_kernel<<<dim3(2048), dim3(256), 0, stream>>>(A, W, Wsc, Ah, Wh);
        const int nwg = (M / BM) * (N / BN);  // 256
        qgemm32x32_kernel<<<dim3(nwg), dim3(512), 0, stream>>>(Ah, Wh, bias, C);
    } else {
        const int nwg = (M / 128) * (N / 128);
        qlinear_fused_kernel<<<dim3(nwg), dim3(256), 0, stream>>>(A, W, Wsc, bias, C);
    }
}

// Round 16
// 202.023 us; speedup vs baseline: 1.2547x; 1.2547x over previous
//
#include <hip/hip_runtime.h>
#include <hip/hip_fp16.h>

typedef _Float16 half8 __attribute__((ext_vector_type(8)));
typedef float f32x4 __attribute__((ext_vector_type(4)));

constexpr int M = 2048;    // B*S
constexpr int N = 10240;   // DOUT
constexpr int K = 4096;    // DIN

// ---------------------------------------------------------------------------
// Fused pre-pass: A fp32->fp16 (exact) + W fp32 -> fp16*fp16(scale)
// (bit-identical to reference). Branch is block-uniform except one block.
constexpr long A_VEC = (long)M * K / 8;   // 1,048,576
constexpr long W_VEC = (long)N * K / 8;   // 5,242,880

__global__ __launch_bounds__(256)
void prep_kernel(const float* __restrict__ A, const float* __restrict__ W,
                 const float* __restrict__ Wsc,
                 _Float16* __restrict__ Ah, _Float16* __restrict__ Wh) {
    const long total = A_VEC + W_VEC;
    for (long i = (long)blockIdx.x * blockDim.x + threadIdx.x; i < total;
         i += (long)gridDim.x * blockDim.x) {
        if (i < A_VEC) {
            const long base = i * 8;
            const float4 a0 = ((const float4*)(A + base))[0];
            const float4 a1 = ((const float4*)(A + base))[1];
            half8 h;
            h[0] = (_Float16)a0.x; h[1] = (_Float16)a0.y;
            h[2] = (_Float16)a0.z; h[3] = (_Float16)a0.w;
            h[4] = (_Float16)a1.x; h[5] = (_Float16)a1.y;
            h[6] = (_Float16)a1.z; h[7] = (_Float16)a1.w;
            *(half8*)(Ah + base) = h;
        } else {
            const long base = (i - A_VEC) * 8;
            const int row = (int)(base >> 12);           // / K
            const _Float16 s = (_Float16)Wsc[row];
            const float4 w0 = ((const float4*)(W + base))[0];
            const float4 w1 = ((const float4*)(W + base))[1];
            half8 h;
            h[0] = (_Float16)w0.x * s; h[1] = (_Float16)w0.y * s;
            h[2] = (_Float16)w0.z * s; h[3] = (_Float16)w0.w * s;
            h[4] = (_Float16)w1.x * s; h[5] = (_Float16)w1.y * s;
            h[6] = (_Float16)w1.z * s; h[7] = (_Float16)w1.w * s;
            *(half8*)(Wh + base) = h;
        }
    }
}

// ---------------------------------------------------------------------------
// BEST-KNOWN GEMM (round 11/13, 175.7us / 978 TF / 43% MfmaUtil) — restored
// verbatim. 256x320, grid 8x32 = 256 blocks = 1 block/CU, ZERO tail.
// 8 waves (2M x 4N) of 128x80. kh-SPLIT 3-phase schedule: live operand set
// is one kh-slice (a[8]+b[5] = 52 VGPR), acc[8][5] = 160 AGPR.
//   P0: 13 ds_reads (kh0) -> 40 MFMA (all rb x cb, kh0)
//   P1: 13 ds_reads (kh1) -> 20 MFMA (rb 0..3, kh1); LGKM0+BAR (regions free)
//   P2: stage t+2 (9 gload_lds, distance-2) -> 20 MFMA (rb 4..7, kh1);
//       vmcnt(9) [t+1 landed, t+2 in flight]; BAR publishes t+1.
// T2 swizzle: linear gload_lds dest + pre-swizzled src col + swizzled read.
// NOTE: r12 finer phases (-97us), r14 read-reorder (null), r15 32x32 MFMA
// (bank conflicts, -45us), r4/r6 quadrant phases, r8 bigger wave tiles
// (spill), r9 B-streaming, r10 2-co-resident all REGRESSED or null —
// keep this exact 2-barrier + counted-vmcnt shape.
constexpr int BM = 256, BN = 320, BK = 64;
constexpr int AELE = BM * BK;   // 16384 fp16 = 32 KB
constexpr int BELE = BN * BK;   // 20480 fp16 = 40 KB
constexpr int NT = K / BK;      // 64 K-tiles

#define BAR()   asm volatile("s_barrier" ::: "memory")
#define LGKM0() asm volatile("s_waitcnt lgkmcnt(0)" ::: "memory")

__device__ __forceinline__ half8 lds_rd(const _Float16* base, int row, int eo) {
    // T2: physical 16B slot = slot ^ (row&7)
    const int ps = (eo >> 3) ^ (row & 7);
    return *(const half8*)(base + row * BK + ps * 8);
}

__global__ __launch_bounds__(512, 2)
void qgemm256x320v2_kernel(const _Float16* __restrict__ Ag,  // [M,K] fp16 (ws)
                           const _Float16* __restrict__ Wg,  // [N,K] fp16 deq
                           const float*    __restrict__ bias,
                           float*          __restrict__ C)
{
    __shared__ _Float16 AsF[2 * AELE];   // 64 KB
    __shared__ _Float16 BsF[2 * BELE];   // 80 KB  (144 KB total)

    // XCD-bijective swizzle: 256 = 8 chunks x 32; brow-fast -> 8-block runs
    // share one 2.6MB B panel (L2-resident per XCD).
    const int orig = blockIdx.x;
    const int wgid = (orig & 7) * 32 + (orig >> 3);
    const int m0 = (wgid & 7) * BM;
    const int n0 = (wgid >> 3) * BN;

    const int tid  = threadIdx.x;
    const int lane = tid & 63;
    const int w    = tid >> 6;
    const int wm   = w >> 2;            // 0..1 -> rows wm*128
    const int wn   = w & 3;             // 0..3 -> cols wn*80
    const int fr   = lane & 15;
    const int fkE  = (lane >> 4) * 8;

    const int trow  = tid >> 3;                        // staging row 0..63
    const int swcol = (((tid & 7) ^ (trow & 7))) * 8;  // pre-swizzled src col

    // stage unit = 64 rows x 64 cols fp16 = 8 KB = 512 thr x 16 B
    auto stage_a = [&](int b, int u, int kcol) {
        const _Float16* src = Ag + (size_t)(m0 + u * 64 + trow) * K + (kcol + swcol);
        __builtin_amdgcn_global_load_lds(
            (const __attribute__((address_space(1))) void*)src,
            (__attribute__((address_space(3))) void*)(AsF + b * AELE + u * 4096 + tid * 8),
            16, 0, 0);
    };
    auto stage_b = [&](int b, int u, int kcol) {
        const _Float16* src = Wg + (size_t)(n0 + u * 64 + trow) * K + (kcol + swcol);
        __builtin_amdgcn_global_load_lds(
            (const __attribute__((address_space(1))) void*)src,
            (__attribute__((address_space(3))) void*)(BsF + b * BELE + u * 4096 + tid * 8),
            16, 0, 0);
    };

    f32x4 acc[8][5];
#pragma unroll
    for (int i = 0; i < 8; ++i)
#pragma unroll
        for (int j = 0; j < 5; ++j)
            acc[i][j] = (f32x4){0.f, 0.f, 0.f, 0.f};

    // prologue: tile0 -> buf0 (9 loads), tile1 -> buf1 (9 loads)
#pragma unroll
    for (int u = 0; u < 4; ++u) stage_a(0, u, 0);
#pragma unroll
    for (int u = 0; u < 5; ++u) stage_b(0, u, 0);
#pragma unroll
    for (int u = 0; u < 4; ++u) stage_a(1, u, BK);
#pragma unroll
    for (int u = 0; u < 5; ++u) stage_b(1, u, BK);
    asm volatile("s_waitcnt vmcnt(9)" ::: "memory");   // tile0 landed
    BAR();

    const int rowA = wm * 128 + fr;     // A fragment row base
    const int rowB = wn * 80 + fr;      // B fragment row base

#pragma unroll 1
    for (int t = 0; t < NT; ++t) {
        const int cur = t & 1;
        const _Float16* Ab = AsF + cur * AELE;
        const _Float16* Bb = BsF + cur * BELE;
        const bool pf2 = (t + 2 < NT);
        const int k2 = (t + 2) * BK;

        // ---- P0: kh=0 reads (13), then 40 MFMA (all rb x cb, kh0).
        {
            half8 a0[8], b0[5];
#pragma unroll
            for (int rb = 0; rb < 8; ++rb)
                a0[rb] = lds_rd(Ab, rowA + rb * 16, fkE);
#pragma unroll
            for (int cb = 0; cb < 5; ++cb)
                b0[cb] = lds_rd(Bb, rowB + cb * 16, fkE);
            __builtin_amdgcn_s_setprio(1);
#pragma unroll
            for (int rb = 0; rb < 8; ++rb)
#pragma unroll
                for (int cb = 0; cb < 5; ++cb)
                    acc[rb][cb] = __builtin_amdgcn_mfma_f32_16x16x32_f16(
                        a0[rb], b0[cb], acc[rb][cb], 0, 0, 0);
            __builtin_amdgcn_s_setprio(0);
        }

        // ---- P1: kh=1 reads (13), 20 MFMA (rb 0..3); LGKM0+BAR frees bufs.
        half8 a1[8], b1[5];
#pragma unroll
        for (int rb = 0; rb < 8; ++rb)
            a1[rb] = lds_rd(Ab, rowA + rb * 16, 32 + fkE);
#pragma unroll
        for (int cb = 0; cb < 5; ++cb)
            b1[cb] = lds_rd(Bb, rowB + cb * 16, 32 + fkE);
        __builtin_amdgcn_s_setprio(1);
#pragma unroll
        for (int rb = 0; rb < 4; ++rb)
#pragma unroll
            for (int cb = 0; cb < 5; ++cb)
                acc[rb][cb] = __builtin_amdgcn_mfma_f32_16x16x32_f16(
                    a1[rb], b1[cb], acc[rb][cb], 0, 0, 0);
        __builtin_amdgcn_s_setprio(0);
        LGKM0();   // all own reads of cur complete (cross-wave stage safety)
        BAR();     // every wave done reading A(cur)+B(cur)

        // ---- P2: stage t+2 into cur; 20 MFMA (rb 4..7, reg-only); vmcnt.
        if (pf2) {
#pragma unroll
            for (int u = 0; u < 4; ++u) stage_a(cur, u, k2);
#pragma unroll
            for (int u = 0; u < 5; ++u) stage_b(cur, u, k2);
        }
        __builtin_amdgcn_s_setprio(1);
#pragma unroll
        for (int rb = 4; rb < 8; ++rb)
#pragma unroll
            for (int cb = 0; cb < 5; ++cb)
                acc[rb][cb] = __builtin_amdgcn_mfma_f32_16x16x32_f16(
                    a1[rb], b1[cb], acc[rb][cb], 0, 0, 0);
        __builtin_amdgcn_s_setprio(0);
        if (pf2) asm volatile("s_waitcnt vmcnt(9)" ::: "memory");  // t+1 landed
        else     asm volatile("s_waitcnt vmcnt(0)" ::: "memory");  // tail drain
        BAR();   // publish t+1
    }

    // epilogue: C/D layout col = lane&15, row = (lane>>4)*4 + reg
    float bb[5];
#pragma unroll
    for (int j = 0; j < 5; ++j)
        bb[j] = bias[n0 + wn * 80 + j * 16 + fr];
#pragma unroll
    for (int i = 0; i < 8; ++i) {
        const int row = m0 + wm * 128 + i * 16 + (lane >> 4) * 4;
#pragma unroll
        for (int j = 0; j < 5; ++j) {
            const int col = n0 + wn * 80 + j * 16 + fr;
#pragma unroll
            for (int r = 0; r < 4; ++r)
                C[(size_t)(row + r) * N + col] =
                    (float)(_Float16)(acc[i][j][r] + bb[j]);
        }
    }
}

// ---------------------------------------------------------------------------
// Fallback (round-2 fused kernel, passing @434us) if ws too small.
__global__ __launch_bounds__(256, 2)
void qlinear_fused_kernel(const float* __restrict__ A, const float* __restrict__ W,
                          const float* __restrict__ Wsc, const float* __restrict__ bias,
                          float* __restrict__ C)
{
    __shared__ _Float16 As[128][64];
    __shared__ _Float16 Bs[128][64];

    const int nwg  = (M / 128) * (N / 128);
    const int orig = blockIdx.x;
    const int wgid = (orig & 7) * (nwg >> 3) + (orig >> 3);
    const int brow = wgid & (M / 128 - 1);
    const int bcol = wgid / (M / 128);
    const int m0 = brow * 128;
    const int n0 = bcol * 128;

    const int t    = threadIdx.x;
    const int lane = t & 63;
    const int wave = t >> 6;
    const int wr = (wave >> 1) * 64;
    const int wc = (wave & 1) * 64;
    const int fr = lane & 15;
    const int fk = (lane >> 4) * 8;
    const int srow = t >> 3;
    const int scol = (t & 7) * 8;

    _Float16 hs[4];
#pragma unroll
    for (int p = 0; p < 4; ++p)
        hs[p] = (_Float16)Wsc[n0 + srow + p * 32];

    f32x4 acc[4][4];
#pragma unroll
    for (int i = 0; i < 4; ++i)
#pragma unroll
        for (int j = 0; j < 4; ++j)
            acc[i][j] = (f32x4){0.f, 0.f, 0.f, 0.f};

    for (int k0 = 0; k0 < K; k0 += 64) {
        __syncthreads();
#pragma unroll
        for (int c = 0; c < 4; ++c) {
            const int rl = c * 32 + srow;
            const float* asrc = A + (size_t)(m0 + rl) * K + (k0 + scol);
            const float4 a0 = ((const float4*)asrc)[0];
            const float4 a1 = ((const float4*)asrc)[1];
            half8 av;
            av[0] = (_Float16)a0.x; av[1] = (_Float16)a0.y;
            av[2] = (_Float16)a0.z; av[3] = (_Float16)a0.w;
            av[4] = (_Float16)a1.x; av[5] = (_Float16)a1.y;
            av[6] = (_Float16)a1.z; av[7] = (_Float16)a1.w;
            *(half8*)&As[rl][scol] = av;
        }
#pragma unroll
        for (int p = 0; p < 4; ++p) {
            const int nl = srow + p * 32;
            const float* wsrc = W + (size_t)(n0 + nl) * K + (k0 + scol);
            const float4 w0 = ((const float4*)wsrc)[0];
            const float4 w1 = ((const float4*)wsrc)[1];
            half8 hv;
            hv[0] = (_Float16)w0.x * hs[p]; hv[1] = (_Float16)w0.y * hs[p];
            hv[2] = (_Float16)w0.z * hs[p]; hv[3] = (_Float16)w0.w * hs[p];
            hv[4] = (_Float16)w1.x * hs[p]; hv[5] = (_Float16)w1.y * hs[p];
            hv[6] = (_Float16)w1.z * hs[p]; hv[7] = (_Float16)w1.w * hs[p];
            *(half8*)&Bs[nl][scol] = hv;
        }
        __syncthreads();
#pragma unroll
        for (int kk = 0; kk < 64; kk += 32) {
            half8 av[4], bv[4];
#pragma unroll
            for (int i = 0; i < 4; ++i)
                av[i] = *(const half8*)&As[wr + i * 16 + fr][kk + fk];
#pragma unroll
            for (int j = 0; j < 4; ++j)
                bv[j] = *(const half8*)&Bs[wc + j * 16 + fr][kk + fk];
#pragma unroll
            for (int i = 0; i < 4; ++i)
#pragma unroll
                for (int j = 0; j < 4; ++j)
                    acc[i][j] = __builtin_amdgcn_mfma_f32_16x16x32_f16(
                        av[i], bv[j], acc[i][j], 0, 0, 0);
        }
    }
#pragma unroll
    for (int i = 0; i < 4; ++i) {
        const int row = m0 + wr + i * 16 + (lane >> 4) * 4;
#pragma unroll
        for (int j = 0; j < 4; ++j) {
            const int col = n0 + wc + j * 16 + fr;
            const float bbf = bias[col];
#pragma unroll
            for (int r = 0; r < 4; ++r)
                C[(size_t)(row + r) * N + col] =
                    (float)(_Float16)(acc[i][j][r] + bbf);
        }
    }
}

extern "C" void kernel_launch(void* const* d_in, const int* in_sizes, int n_in,
                              void* d_out, int out_size, void* d_ws, size_t ws_size,
                              hipStream_t stream) {
    const float* A    = (const float*)d_in[0];
    const float* W    = (const float*)d_in[1];
    const float* Wsc  = (const float*)d_in[2];
    const float* bias = (const float*)d_in[3];
    float* C = (float*)d_out;

    const size_t a_bytes = (size_t)M * K * sizeof(_Float16);   // 16.78 MB
    const size_t w_bytes = (size_t)N * K * sizeof(_Float16);   // 83.89 MB

    if (ws_size >= a_bytes + w_bytes) {
        _Float16* Ah = (_Float16*)d_ws;
        _Float16* Wh = (_Float16*)((char*)d_ws + a_bytes);
        prep_kernel<<<dim3(2048), dim3(256), 0, stream>>>(A, W, Wsc, Ah, Wh);
        const int nwg = (M / BM) * (N / BN);  // 256
        qgemm256x320v2_kernel<<<dim3(nwg), dim3(512), 0, stream>>>(Ah, Wh, bias, C);
    } else {
        const int nwg = (M / 128) * (N / 128);
        qlinear_fused_kernel<<<dim3(nwg), dim3(256), 0, stream>>>(A, W, Wsc, bias, C);
    }
}

// Round 17
// 201.164 us; speedup vs baseline: 1.2600x; 1.0043x over previous
//
#include <hip/hip_runtime.h>
#include <hip/hip_fp16.h>

typedef _Float16 half8 __attribute__((ext_vector_type(8)));
typedef float f32x4 __attribute__((ext_vector_type(4)));

constexpr int M = 2048;    // B*S
constexpr int N = 10240;   // DOUT
constexpr int K = 4096;    // DIN

// ---------------------------------------------------------------------------
// Fused pre-pass: A fp32->fp16 (exact) + W fp32 -> fp16*fp16(scale)
// (bit-identical to reference). Branch is block-uniform except one block.
constexpr long A_VEC = (long)M * K / 8;   // 1,048,576
constexpr long W_VEC = (long)N * K / 8;   // 5,242,880

__global__ __launch_bounds__(256)
void prep_kernel(const float* __restrict__ A, const float* __restrict__ W,
                 const float* __restrict__ Wsc,
                 _Float16* __restrict__ Ah, _Float16* __restrict__ Wh) {
    const long total = A_VEC + W_VEC;
    for (long i = (long)blockIdx.x * blockDim.x + threadIdx.x; i < total;
         i += (long)gridDim.x * blockDim.x) {
        if (i < A_VEC) {
            const long base = i * 8;
            const float4 a0 = ((const float4*)(A + base))[0];
            const float4 a1 = ((const float4*)(A + base))[1];
            half8 h;
            h[0] = (_Float16)a0.x; h[1] = (_Float16)a0.y;
            h[2] = (_Float16)a0.z; h[3] = (_Float16)a0.w;
            h[4] = (_Float16)a1.x; h[5] = (_Float16)a1.y;
            h[6] = (_Float16)a1.z; h[7] = (_Float16)a1.w;
            *(half8*)(Ah + base) = h;
        } else {
            const long base = (i - A_VEC) * 8;
            const int row = (int)(base >> 12);           // / K
            const _Float16 s = (_Float16)Wsc[row];
            const float4 w0 = ((const float4*)(W + base))[0];
            const float4 w1 = ((const float4*)(W + base))[1];
            half8 h;
            h[0] = (_Float16)w0.x * s; h[1] = (_Float16)w0.y * s;
            h[2] = (_Float16)w0.z * s; h[3] = (_Float16)w0.w * s;
            h[4] = (_Float16)w1.x * s; h[5] = (_Float16)w1.y * s;
            h[6] = (_Float16)w1.z * s; h[7] = (_Float16)w1.w * s;
            *(half8*)(Wh + base) = h;
        }
    }
}

// ---------------------------------------------------------------------------
// FINAL GEMM (best-known, rounds 11/13/16: 202us total, 43-48% MfmaUtil).
// 256x320, grid 8x32 = 256 blocks = 1 block/CU, ZERO tail.
// 8 waves (2M x 4N) of 128x80. kh-SPLIT 3-phase schedule: live operand set
// is one kh-slice (a[8]+b[5] = 52 VGPR), acc[8][5] = 160 AGPR.
//   P0: 13 ds_reads (kh0) -> 40 MFMA (all rb x cb, kh0)
//   P1: 13 ds_reads (kh1) -> 20 MFMA (rb 0..3, kh1); LGKM0+BAR (regions free)
//   P2: stage t+2 (9 gload_lds, distance-2) -> 20 MFMA (rb 4..7, kh1);
//       vmcnt(9) [t+1 landed, t+2 in flight]; BAR publishes t+1.
// T2 swizzle: linear gload_lds dest + pre-swizzled src col + swizzled read.
// SESSION LEDGER (do not revisit): fused dequant 434; m97-128sq 275;
// quadrant-phases 298/281; fine sub-phases 308; B-streaming 374;
// 2-co-resident 218; read-reorder null; 32x32 MFMA 253 (4-way LDS conflict
// inherent at BK=64); bigger wave tiles spill (>256 unified regs).
constexpr int BM = 256, BN = 320, BK = 64;
constexpr int AELE = BM * BK;   // 16384 fp16 = 32 KB
constexpr int BELE = BN * BK;   // 20480 fp16 = 40 KB
constexpr int NT = K / BK;      // 64 K-tiles

#define BAR()   asm volatile("s_barrier" ::: "memory")
#define LGKM0() asm volatile("s_waitcnt lgkmcnt(0)" ::: "memory")

__device__ __forceinline__ half8 lds_rd(const _Float16* base, int row, int eo) {
    // T2: physical 16B slot = slot ^ (row&7)
    const int ps = (eo >> 3) ^ (row & 7);
    return *(const half8*)(base + row * BK + ps * 8);
}

__global__ __launch_bounds__(512, 2)
void qgemm256x320v2_kernel(const _Float16* __restrict__ Ag,  // [M,K] fp16 (ws)
                           const _Float16* __restrict__ Wg,  // [N,K] fp16 deq
                           const float*    __restrict__ bias,
                           float*          __restrict__ C)
{
    __shared__ _Float16 AsF[2 * AELE];   // 64 KB
    __shared__ _Float16 BsF[2 * BELE];   // 80 KB  (144 KB total)

    // XCD-bijective swizzle: 256 = 8 chunks x 32; brow-fast -> 8-block runs
    // share one 2.6MB B panel (L2-resident per XCD).
    const int orig = blockIdx.x;
    const int wgid = (orig & 7) * 32 + (orig >> 3);
    const int m0 = (wgid & 7) * BM;
    const int n0 = (wgid >> 3) * BN;

    const int tid  = threadIdx.x;
    const int lane = tid & 63;
    const int w    = tid >> 6;
    const int wm   = w >> 2;            // 0..1 -> rows wm*128
    const int wn   = w & 3;             // 0..3 -> cols wn*80
    const int fr   = lane & 15;
    const int fkE  = (lane >> 4) * 8;

    const int trow  = tid >> 3;                        // staging row 0..63
    const int swcol = (((tid & 7) ^ (trow & 7))) * 8;  // pre-swizzled src col

    // stage unit = 64 rows x 64 cols fp16 = 8 KB = 512 thr x 16 B
    auto stage_a = [&](int b, int u, int kcol) {
        const _Float16* src = Ag + (size_t)(m0 + u * 64 + trow) * K + (kcol + swcol);
        __builtin_amdgcn_global_load_lds(
            (const __attribute__((address_space(1))) void*)src,
            (__attribute__((address_space(3))) void*)(AsF + b * AELE + u * 4096 + tid * 8),
            16, 0, 0);
    };
    auto stage_b = [&](int b, int u, int kcol) {
        const _Float16* src = Wg + (size_t)(n0 + u * 64 + trow) * K + (kcol + swcol);
        __builtin_amdgcn_global_load_lds(
            (const __attribute__((address_space(1))) void*)src,
            (__attribute__((address_space(3))) void*)(BsF + b * BELE + u * 4096 + tid * 8),
            16, 0, 0);
    };

    f32x4 acc[8][5];
#pragma unroll
    for (int i = 0; i < 8; ++i)
#pragma unroll
        for (int j = 0; j < 5; ++j)
            acc[i][j] = (f32x4){0.f, 0.f, 0.f, 0.f};

    // prologue: tile0 -> buf0 (9 loads), tile1 -> buf1 (9 loads)
#pragma unroll
    for (int u = 0; u < 4; ++u) stage_a(0, u, 0);
#pragma unroll
    for (int u = 0; u < 5; ++u) stage_b(0, u, 0);
#pragma unroll
    for (int u = 0; u < 4; ++u) stage_a(1, u, BK);
#pragma unroll
    for (int u = 0; u < 5; ++u) stage_b(1, u, BK);
    asm volatile("s_waitcnt vmcnt(9)" ::: "memory");   // tile0 landed
    BAR();

    const int rowA = wm * 128 + fr;     // A fragment row base
    const int rowB = wn * 80 + fr;      // B fragment row base

#pragma unroll 1
    for (int t = 0; t < NT; ++t) {
        const int cur = t & 1;
        const _Float16* Ab = AsF + cur * AELE;
        const _Float16* Bb = BsF + cur * BELE;
        const bool pf2 = (t + 2 < NT);
        const int k2 = (t + 2) * BK;

        // ---- P0: kh=0 reads (13), then 40 MFMA (all rb x cb, kh0).
        {
            half8 a0[8], b0[5];
#pragma unroll
            for (int rb = 0; rb < 8; ++rb)
                a0[rb] = lds_rd(Ab, rowA + rb * 16, fkE);
#pragma unroll
            for (int cb = 0; cb < 5; ++cb)
                b0[cb] = lds_rd(Bb, rowB + cb * 16, fkE);
            __builtin_amdgcn_s_setprio(1);
#pragma unroll
            for (int rb = 0; rb < 8; ++rb)
#pragma unroll
                for (int cb = 0; cb < 5; ++cb)
                    acc[rb][cb] = __builtin_amdgcn_mfma_f32_16x16x32_f16(
                        a0[rb], b0[cb], acc[rb][cb], 0, 0, 0);
            __builtin_amdgcn_s_setprio(0);
        }

        // ---- P1: kh=1 reads (13), 20 MFMA (rb 0..3); LGKM0+BAR frees bufs.
        half8 a1[8], b1[5];
#pragma unroll
        for (int rb = 0; rb < 8; ++rb)
            a1[rb] = lds_rd(Ab, rowA + rb * 16, 32 + fkE);
#pragma unroll
        for (int cb = 0; cb < 5; ++cb)
            b1[cb] = lds_rd(Bb, rowB + cb * 16, 32 + fkE);
        __builtin_amdgcn_s_setprio(1);
#pragma unroll
        for (int rb = 0; rb < 4; ++rb)
#pragma unroll
            for (int cb = 0; cb < 5; ++cb)
                acc[rb][cb] = __builtin_amdgcn_mfma_f32_16x16x32_f16(
                    a1[rb], b1[cb], acc[rb][cb], 0, 0, 0);
        __builtin_amdgcn_s_setprio(0);
        LGKM0();   // all own reads of cur complete (cross-wave stage safety)
        BAR();     // every wave done reading A(cur)+B(cur)

        // ---- P2: stage t+2 into cur; 20 MFMA (rb 4..7, reg-only); vmcnt.
        if (pf2) {
#pragma unroll
            for (int u = 0; u < 4; ++u) stage_a(cur, u, k2);
#pragma unroll
            for (int u = 0; u < 5; ++u) stage_b(cur, u, k2);
        }
        __builtin_amdgcn_s_setprio(1);
#pragma unroll
        for (int rb = 4; rb < 8; ++rb)
#pragma unroll
            for (int cb = 0; cb < 5; ++cb)
                acc[rb][cb] = __builtin_amdgcn_mfma_f32_16x16x32_f16(
                    a1[rb], b1[cb], acc[rb][cb], 0, 0, 0);
        __builtin_amdgcn_s_setprio(0);
        if (pf2) asm volatile("s_waitcnt vmcnt(9)" ::: "memory");  // t+1 landed
        else     asm volatile("s_waitcnt vmcnt(0)" ::: "memory");  // tail drain
        BAR();   // publish t+1
    }

    // epilogue: C/D layout col = lane&15, row = (lane>>4)*4 + reg
    float bb[5];
#pragma unroll
    for (int j = 0; j < 5; ++j)
        bb[j] = bias[n0 + wn * 80 + j * 16 + fr];
#pragma unroll
    for (int i = 0; i < 8; ++i) {
        const int row = m0 + wm * 128 + i * 16 + (lane >> 4) * 4;
#pragma unroll
        for (int j = 0; j < 5; ++j) {
            const int col = n0 + wn * 80 + j * 16 + fr;
#pragma unroll
            for (int r = 0; r < 4; ++r)
                C[(size_t)(row + r) * N + col] =
                    (float)(_Float16)(acc[i][j][r] + bb[j]);
        }
    }
}

// ---------------------------------------------------------------------------
// Fallback (round-2 fused kernel, passing @434us) if ws too small.
__global__ __launch_bounds__(256, 2)
void qlinear_fused_kernel(const float* __restrict__ A, const float* __restrict__ W,
                          const float* __restrict__ Wsc, const float* __restrict__ bias,
                          float* __restrict__ C)
{
    __shared__ _Float16 As[128][64];
    __shared__ _Float16 Bs[128][64];

    const int nwg  = (M / 128) * (N / 128);
    const int orig = blockIdx.x;
    const int wgid = (orig & 7) * (nwg >> 3) + (orig >> 3);
    const int brow = wgid & (M / 128 - 1);
    const int bcol = wgid / (M / 128);
    const int m0 = brow * 128;
    const int n0 = bcol * 128;

    const int t    = threadIdx.x;
    const int lane = t & 63;
    const int wave = t >> 6;
    const int wr = (wave >> 1) * 64;
    const int wc = (wave & 1) * 64;
    const int fr = lane & 15;
    const int fk = (lane >> 4) * 8;
    const int srow = t >> 3;
    const int scol = (t & 7) * 8;

    _Float16 hs[4];
#pragma unroll
    for (int p = 0; p < 4; ++p)
        hs[p] = (_Float16)Wsc[n0 + srow + p * 32];

    f32x4 acc[4][4];
#pragma unroll
    for (int i = 0; i < 4; ++i)
#pragma unroll
        for (int j = 0; j < 4; ++j)
            acc[i][j] = (f32x4){0.f, 0.f, 0.f, 0.f};

    for (int k0 = 0; k0 < K; k0 += 64) {
        __syncthreads();
#pragma unroll
        for (int c = 0; c < 4; ++c) {
            const int rl = c * 32 + srow;
            const float* asrc = A + (size_t)(m0 + rl) * K + (k0 + scol);
            const float4 a0 = ((const float4*)asrc)[0];
            const float4 a1 = ((const float4*)asrc)[1];
            half8 av;
            av[0] = (_Float16)a0.x; av[1] = (_Float16)a0.y;
            av[2] = (_Float16)a0.z; av[3] = (_Float16)a0.w;
            av[4] = (_Float16)a1.x; av[5] = (_Float16)a1.y;
            av[6] = (_Float16)a1.z; av[7] = (_Float16)a1.w;
            *(half8*)&As[rl][scol] = av;
        }
#pragma unroll
        for (int p = 0; p < 4; ++p) {
            const int nl = srow + p * 32;
            const float* wsrc = W + (size_t)(n0 + nl) * K + (k0 + scol);
            const float4 w0 = ((const float4*)wsrc)[0];
            const float4 w1 = ((const float4*)wsrc)[1];
            half8 hv;
            hv[0] = (_Float16)w0.x * hs[p]; hv[1] = (_Float16)w0.y * hs[p];
            hv[2] = (_Float16)w0.z * hs[p]; hv[3] = (_Float16)w0.w * hs[p];
            hv[4] = (_Float16)w1.x * hs[p]; hv[5] = (_Float16)w1.y * hs[p];
            hv[6] = (_Float16)w1.z * hs[p]; hv[7] = (_Float16)w1.w * hs[p];
            *(half8*)&Bs[nl][scol] = hv;
        }
        __syncthreads();
#pragma unroll
        for (int kk = 0; kk < 64; kk += 32) {
            half8 av[4], bv[4];
#pragma unroll
            for (int i = 0; i < 4; ++i)
                av[i] = *(const half8*)&As[wr + i * 16 + fr][kk + fk];
#pragma unroll
            for (int j = 0; j < 4; ++j)
                bv[j] = *(const half8*)&Bs[wc + j * 16 + fr][kk + fk];
#pragma unroll
            for (int i = 0; i < 4; ++i)
#pragma unroll
                for (int j = 0; j < 4; ++j)
                    acc[i][j] = __builtin_amdgcn_mfma_f32_16x16x32_f16(
                        av[i], bv[j], acc[i][j], 0, 0, 0);
        }
    }
#pragma unroll
    for (int i = 0; i < 4; ++i) {
        const int row = m0 + wr + i * 16 + (lane >> 4) * 4;
#pragma unroll
        for (int j = 0; j < 4; ++j) {
            const int col = n0 + wc + j * 16 + fr;
            const float bbf = bias[col];
#pragma unroll
            for (int r = 0; r < 4; ++r)
                C[(size_t)(row + r) * N + col] =
                    (float)(_Float16)(acc[i][j][r] + bbf);
        }
    }
}

extern "C" void kernel_launch(void* const* d_in, const int* in_sizes, int n_in,
                              void* d_out, int out_size, void* d_ws, size_t ws_size,
                              hipStream_t stream) {
    const float* A    = (const float*)d_in[0];
    const float* W    = (const float*)d_in[1];
    const float* Wsc  = (const float*)d_in[2];
    const float* bias = (const float*)d_in[3];
    float* C = (float*)d_out;

    const size_t a_bytes = (size_t)M * K * sizeof(_Float16);   // 16.78 MB
    const size_t w_bytes = (size_t)N * K * sizeof(_Float16);   // 83.89 MB

    if (ws_size >= a_bytes + w_bytes) {
        _Float16* Ah = (_Float16*)d_ws;
        _Float16* Wh = (_Float16*)((char*)d_ws + a_bytes);
        prep_kernel<<<dim3(2048), dim3(256), 0, stream>>>(A, W, Wsc, Ah, Wh);
        const int nwg = (M / BM) * (N / BN);  // 256
        qgemm256x320v2_kernel<<<dim3(nwg), dim3(512), 0, stream>>>(Ah, Wh, bias, C);
    } else {
        const int nwg = (M / 128) * (N / 128);
        qlinear_fused_kernel<<<dim3(nwg), dim3(256), 0, stream>>>(A, W, Wsc, bias, C);
    }
}